// Round 4
// baseline (93.203 us; speedup 1.0000x reference)
//
#include <hip/hip_runtime.h>

#define IN_F   1024
#define OUT_F  1024
#define BATCH  32
#define KCOEF  97
#define CROWS  32                    // rows per chunk
#define CFLOATS (CROWS * KCOEF)      // 3104 floats = 12416 B
#define NCHUNK (IN_F / CROWS)        // 32

typedef float f4 __attribute__((ext_vector_type(4)));

// Kernel A: per (b,i) -> 4 Lagrange basis values + dword offset (id*3) in row.
__global__ __launch_bounds__(256)
void precompute_kernel(const float* __restrict__ x,
                       f4* __restrict__ basis,
                       int* __restrict__ offw) {
    int e = blockIdx.x * 256 + threadIdx.x;   // e = b*IN_F + i
    int b = e >> 10, i = e & 1023;
    float xv = x[e];

    float s = (xv + 1.0f) * 16.0f;            // matches ref rounding exactly
    int id = (int)s;
    id = id < 0 ? 0 : (id > 31 ? 31 : id);

    float d  = xv - ((float)id * 0.0625f - 1.0f);
    float tt = fmaf(d, 32.0f, -1.0f);

    float ap = tt + 1.0f, bp = tt + 0.5f, cm = tt - 0.5f, dm = tt - 1.0f;
    float uu = bp * cm, vv = ap * dm;
    f4 bs;
    bs.x = uu * dm * (-2.0f / 3.0f);
    bs.y = vv * cm * ( 4.0f / 3.0f);
    bs.z = vv * bp * (-4.0f / 3.0f);
    bs.w = uu * ap * ( 2.0f / 3.0f);

    basis[(i << 5) + b] = bs;
    offw [(i << 5) + b] = id * 3;
}

// issue chunk c's global loads into stage regs (13th load: threads 0..31)
#define ISSUE(S, c) do {                                                  \
    const float* _src = wslice + (size_t)(c) * CFLOATS;                   \
    _Pragma("unroll")                                                     \
    for (int _u = 0; _u < 12; ++_u) S[_u] = _src[t + (_u << 8)];          \
    if (t < 32) S[12] = _src[t + 3072];                                   \
} while (0)

// write stage regs to LDS buffer rbuf (compiler emits counted vmcnt wait)
#define WRITE(S, rbuf) do {                                               \
    float* _dst = sh + (rbuf) * CFLOATS;                                  \
    _Pragma("unroll")                                                     \
    for (int _u = 0; _u < 12; ++_u) _dst[t + (_u << 8)] = S[_u];          \
    if (t < 32) _dst[t + 3072] = S[12];                                   \
} while (0)

// gather+fma for chunk c out of LDS buffer rbuf
#define COMPUTE(c, rbuf) do {                                             \
    const float* _rows = sh + (rbuf) * CFLOATS + (g << 2) * KCOEF;        \
    const int _ibase = (c) * CROWS + (g << 2);                            \
    _Pragma("unroll")                                                     \
    for (int _r = 0; _r < 4; ++_r) {                                      \
        const int _idx = ((_ibase + _r) << 5) + b;                        \
        f4 _bs  = basis[_idx];                                            \
        int _j3 = offw[_idx];                                             \
        const float* _row = _rows + _r * KCOEF;                           \
        float _w0 = _row[_j3], _w1 = _row[_j3 + 1];                       \
        float _w2 = _row[_j3 + 2], _w3 = _row[_j3 + 3];                   \
        float _v = fmaf(_bs.x, _w0, fmaf(_bs.y, _w1,                      \
                   fmaf(_bs.z, _w2, _bs.w * _w3)));                       \
        if (_r & 1) acc1 += _v; else acc0 += _v;                          \
    }                                                                     \
} while (0)

// raw barrier: drain LDS ops only; global loads stay in flight (no vmcnt(0))
#define BAR() do {                                                        \
    asm volatile("s_waitcnt lgkmcnt(0)" ::: "memory");                    \
    __builtin_amdgcn_sched_barrier(0);                                    \
    __builtin_amdgcn_s_barrier();                                         \
    __builtin_amdgcn_sched_barrier(0);                                    \
} while (0)

// Kernel B: one block per o. Pure coalesced stream of the 397KB w-slice
// through a 3-buffer LDS pipeline, 2 chunks of prefetch always in flight.
__global__ __launch_bounds__(256, 4)
void piecewise_main(const f4* __restrict__ basis,
                    const int* __restrict__ offw,
                    const float* __restrict__ w,
                    float* __restrict__ out) {
    const int o = blockIdx.x;
    const int t = threadIdx.x;
    const int b = t & 31;     // batch lane
    const int g = t >> 5;     // row-group 0..7 (4 rows each per chunk)

    __shared__ float sh[3 * CFLOATS];
    __shared__ float red[256];

    const float* wslice = w + (size_t)o * (IN_F * KCOEF);

    float sA[13], sB[13];
    float acc0 = 0.f, acc1 = 0.f;

    // prologue: chunk0 -> sA, chunk1 -> sB, write chunk0 to buf0
    ISSUE(sA, 0);
    ISSUE(sB, 1);
    WRITE(sA, 0);
    BAR();

    int rb = 0;   // buffer index of the chunk being computed
    for (int c = 0; c < NCHUNK; c += 2) {
        // even iteration: compute c, write c+1, issue c+2
        if (c + 2 < NCHUNK) ISSUE(sA, c + 2);
        WRITE(sB, (rb + 1) % 3);
        COMPUTE(c, rb);
        BAR();
        // odd iteration: compute c+1, write c+2, issue c+3
        if (c + 3 < NCHUNK) ISSUE(sB, c + 3);
        if (c + 2 < NCHUNK) WRITE(sA, (rb + 2) % 3);
        COMPUTE(c + 1, (rb + 1) % 3);
        BAR();
        rb = (rb + 2) % 3;
    }

    // reduce 8 group-partials per (b, o)
    red[t] = acc0 + acc1;
    __syncthreads();
    if (t < 32) {
        float sum = red[t];
        #pragma unroll
        for (int gg = 1; gg < 8; ++gg) sum += red[gg * 32 + t];
        out[t * OUT_F + o] = sum;
    }
}

extern "C" void kernel_launch(void* const* d_in, const int* in_sizes, int n_in,
                              void* d_out, int out_size, void* d_ws, size_t ws_size,
                              hipStream_t stream) {
    const float* x = (const float*)d_in[0];
    const float* w = (const float*)d_in[1];
    float*       out = (float*)d_out;

    f4*  basis = (f4*)d_ws;                                  // 512 KB
    int* offw  = (int*)((char*)d_ws + BATCH * IN_F * 16);    // 128 KB

    precompute_kernel<<<(BATCH * IN_F) / 256, 256, 0, stream>>>(x, basis, offw);
    piecewise_main<<<OUT_F, 256, 0, stream>>>(basis, offw, w, out);
}

// Round 5
// 74.900 us; speedup vs baseline: 1.2444x; 1.2444x over previous
//
#include <hip/hip_runtime.h>

#define IN_F   1024
#define OUT_F  1024
#define KCOEF  97
#define CROWS  32                       // rows per chunk
#define CFLOATS (CROWS * KCOEF)         // 3104 floats = 12416 B
#define NCHUNK (IN_F / CROWS)           // 32
#define XSTRIDE 33                      // padded x-transpose stride
#define XFLOATS (CROWS * XSTRIDE)       // 1056

// load chunk c's w-slice (13 dwords/thread) + x-slice (4 dwords/thread) to regs
#define ISSUE(c) do {                                                     \
    const float* _srcw = wslice + (size_t)(c) * CFLOATS;                  \
    _Pragma("unroll")                                                     \
    for (int _u = 0; _u < 12; ++_u) sw[_u] = _srcw[t + (_u << 8)];        \
    if (t < 32) sw[12] = _srcw[t + 3072];                                 \
    const int _i0 = (c) * CROWS;                                          \
    _Pragma("unroll")                                                     \
    for (int _u = 0; _u < 4; ++_u) {                                      \
        int _e = t + (_u << 8);                                           \
        sx[_u] = x[(_e >> 5) * IN_F + _i0 + (_e & 31)];                   \
    }                                                                     \
} while (0)

// write staged regs to LDS buffer cb_ (compiler emits the vmcnt wait)
#define WRITE(cb_) do {                                                   \
    float* _dw = shw[cb_];                                                \
    _Pragma("unroll")                                                     \
    for (int _u = 0; _u < 12; ++_u) _dw[t + (_u << 8)] = sw[_u];          \
    if (t < 32) _dw[t + 3072] = sw[12];                                   \
    float* _dx = xs[cb_];                                                 \
    _Pragma("unroll")                                                     \
    for (int _u = 0; _u < 4; ++_u) {                                      \
        int _e = t + (_u << 8);                                           \
        _dx[(_e & 31) * XSTRIDE + (_e >> 5)] = sx[_u];                    \
    }                                                                     \
} while (0)

// compute chunk c from LDS buffer cb_: inline basis + 4-coeff LDS gather
#define COMPUTE(cb_) do {                                                 \
    const float* _rows = &shw[cb_][(g << 2) * KCOEF];                     \
    _Pragma("unroll")                                                     \
    for (int _r = 0; _r < 4; ++_r) {                                      \
        float _xv = xs[cb_][((g << 2) + _r) * XSTRIDE + b];               \
        float _s = (_xv + 1.0f) * 16.0f;                                  \
        int _id = (int)_s;                                                \
        _id = _id < 0 ? 0 : (_id > 31 ? 31 : _id);                        \
        float _d  = _xv - ((float)_id * 0.0625f - 1.0f);                  \
        float _tt = fmaf(_d, 32.0f, -1.0f);                               \
        float _ap = _tt + 1.0f, _bp = _tt + 0.5f;                         \
        float _cm = _tt - 0.5f, _dm = _tt - 1.0f;                         \
        float _uu = _bp * _cm, _vv = _ap * _dm;                           \
        float _B0 = _uu * _dm * (-2.0f / 3.0f);                           \
        float _B1 = _vv * _cm * ( 4.0f / 3.0f);                           \
        float _B2 = _vv * _bp * (-4.0f / 3.0f);                           \
        float _B3 = _uu * _ap * ( 2.0f / 3.0f);                           \
        const float* _row = _rows + _r * KCOEF;                           \
        int _j3 = _id * 3;                                                \
        float _w0 = _row[_j3], _w1 = _row[_j3 + 1];                       \
        float _w2 = _row[_j3 + 2], _w3 = _row[_j3 + 3];                   \
        float _v = fmaf(_B0, _w0, fmaf(_B1, _w1,                          \
                   fmaf(_B2, _w2, _B3 * _w3)));                           \
        if (_r & 1) acc1 += _v; else acc0 += _v;                          \
    }                                                                     \
} while (0)

__global__ __launch_bounds__(256, 4)
void piecewise_fused(const float* __restrict__ x,
                     const float* __restrict__ w,
                     float* __restrict__ out) {
    // bijective XCD swizzle: 1024 blocks -> 128 consecutive slices per XCD
    const int bid = blockIdx.x;
    const int o = (bid & 7) * 128 + (bid >> 3);
    const int t = threadIdx.x;
    const int b = t & 31;     // batch lane
    const int g = t >> 5;     // row-group 0..7 (4 rows each)

    __shared__ float shw[2][CFLOATS];
    __shared__ float xs[2][XFLOATS];
    __shared__ float red[256];

    const float* wslice = w + (size_t)o * (IN_F * KCOEF);

    float sw[13], sx[4];
    float acc0 = 0.f, acc1 = 0.f;

    // prologue
    ISSUE(0);
    WRITE(0);
    __syncthreads();

    for (int c = 0; c < NCHUNK; ++c) {
        const int cb = c & 1;
        if (c + 1 < NCHUNK) ISSUE(c + 1);      // loads in flight over compute
        COMPUTE(cb);
        if (c + 1 < NCHUNK) WRITE(cb ^ 1);     // waits the staged loads, writes LDS
        __syncthreads();
    }

    // reduce 8 group-partials per (b, o)
    red[t] = acc0 + acc1;
    __syncthreads();
    if (t < 32) {
        float sum = red[t];
        #pragma unroll
        for (int gg = 1; gg < 8; ++gg) sum += red[gg * 32 + t];
        out[t * OUT_F + o] = sum;
    }
}

extern "C" void kernel_launch(void* const* d_in, const int* in_sizes, int n_in,
                              void* d_out, int out_size, void* d_ws, size_t ws_size,
                              hipStream_t stream) {
    const float* x = (const float*)d_in[0];
    const float* w = (const float*)d_in[1];
    float*       out = (float*)d_out;
    piecewise_fused<<<OUT_F, 256, 0, stream>>>(x, w, out);
}

// Round 6
// 73.787 us; speedup vs baseline: 1.2631x; 1.0151x over previous
//
#include <hip/hip_runtime.h>

#define IN_F   1024
#define OUT_F  1024
#define KCOEF  97
#define CROWS  32                       // rows per chunk
#define CFLOATS (CROWS * KCOEF)         // 3104 floats
#define CBYTES  (CFLOATS * 4)           // 12416 B
#define NCHUNK (IN_F / CROWS)           // 32
#define XSTRIDE 33                      // padded x-transpose stride

typedef float f4 __attribute__((ext_vector_type(4)));

// w-chunk -> LDS via direct DMA (global_load_lds, 16B/lane). Linear dest:
// 3 full-block instrs (4096B each) + one 8-lane tail (128B).
#define ISSUE_W(c, cb_) do {                                                    \
    const char* _base = wslice + (size_t)(c) * CBYTES;                          \
    char* _lbase = (char*)&shw[cb_][0];                                         \
    _Pragma("unroll")                                                           \
    for (int _k = 0; _k < 3; ++_k)                                              \
        __builtin_amdgcn_global_load_lds(                                       \
            (const __attribute__((address_space(1))) void*)(_base + (_k << 12) + (t << 4)), \
            (__attribute__((address_space(3))) void*)(_lbase + (_k << 12) + ((t >> 6) << 10)), \
            16, 0, 0);                                                          \
    if (t < 8)                                                                  \
        __builtin_amdgcn_global_load_lds(                                       \
            (const __attribute__((address_space(1))) void*)(_base + 12288 + (t << 4)), \
            (__attribute__((address_space(3))) void*)(_lbase + 12288),          \
            16, 0, 0);                                                          \
} while (0)

// x-slice: one f4 load per thread (32 b x 32 i per chunk)
#define ISSUE_X(c) do {                                                   \
    sx = *(const f4*)&x[(t >> 3) * IN_F + (c) * CROWS + ((t & 7) << 2)];  \
} while (0)

// transposed x write: [i_local][b], stride 33 -> conflict-free reads
#define WRITE_X(cb_) do {                                                 \
    float* _dx = xsh[cb_];                                                \
    const int _bs = t >> 3, _j4 = (t & 7) << 2;                           \
    _dx[(_j4    ) * XSTRIDE + _bs] = sx.x;                                \
    _dx[(_j4 + 1) * XSTRIDE + _bs] = sx.y;                                \
    _dx[(_j4 + 2) * XSTRIDE + _bs] = sx.z;                                \
    _dx[(_j4 + 3) * XSTRIDE + _bs] = sx.w;                                \
} while (0)

// inline basis + 4-coeff LDS gather for chunk in buffer cb_
#define COMPUTE(cb_) do {                                                 \
    const float* _rows = &shw[cb_][(g << 2) * KCOEF];                     \
    _Pragma("unroll")                                                     \
    for (int _r = 0; _r < 4; ++_r) {                                      \
        float _xv = xsh[cb_][((g << 2) + _r) * XSTRIDE + b];              \
        float _s = (_xv + 1.0f) * 16.0f;                                  \
        int _id = (int)_s;                                                \
        _id = _id < 0 ? 0 : (_id > 31 ? 31 : _id);                        \
        float _d  = _xv - ((float)_id * 0.0625f - 1.0f);                  \
        float _tt = fmaf(_d, 32.0f, -1.0f);                               \
        float _ap = _tt + 1.0f, _bp = _tt + 0.5f;                         \
        float _cm = _tt - 0.5f, _dm = _tt - 1.0f;                         \
        float _uu = _bp * _cm, _vv = _ap * _dm;                           \
        float _B0 = _uu * _dm * (-2.0f / 3.0f);                           \
        float _B1 = _vv * _cm * ( 4.0f / 3.0f);                           \
        float _B2 = _vv * _bp * (-4.0f / 3.0f);                           \
        float _B3 = _uu * _ap * ( 2.0f / 3.0f);                           \
        const float* _row = _rows + _r * KCOEF;                           \
        int _j3 = _id * 3;                                                \
        float _w0 = _row[_j3], _w1 = _row[_j3 + 1];                       \
        float _w2 = _row[_j3 + 2], _w3 = _row[_j3 + 3];                   \
        float _v = fmaf(_B0, _w0, fmaf(_B1, _w1,                          \
                   fmaf(_B2, _w2, _B3 * _w3)));                           \
        if (_r & 1) acc1 += _v; else acc0 += _v;                          \
    }                                                                     \
} while (0)

__global__ __launch_bounds__(256, 4)
void piecewise_fused(const float* __restrict__ x,
                     const float* __restrict__ w,
                     float* __restrict__ out) {
    // bijective XCD swizzle: 1024 % 8 == 0
    const int bid = blockIdx.x;
    const int o = (bid & 7) * 128 + (bid >> 3);
    const int t = threadIdx.x;
    const int b = t & 31;     // batch lane
    const int g = t >> 5;     // row-group 0..7 (4 rows each)

    __shared__ __align__(16) float shw[2][CFLOATS];
    __shared__ float xsh[2][CROWS * XSTRIDE];
    __shared__ float red[256];

    const char* wslice = (const char*)(w + (size_t)o * (IN_F * KCOEF));

    f4 sx;
    float acc0 = 0.f, acc1 = 0.f;

    // prologue: chunk 0 DMA + x stage
    ISSUE_W(0, 0);
    ISSUE_X(0);
    WRITE_X(0);
    __syncthreads();                       // drains DMA + LDS writes

    for (int c = 0; c < NCHUNK; ++c) {
        const int cb = c & 1;
        if (c + 1 < NCHUNK) {
            ISSUE_W(c + 1, cb ^ 1);        // DMA next chunk, in flight over compute
            ISSUE_X(c + 1);
        }
        COMPUTE(cb);
        if (c + 1 < NCHUNK) WRITE_X(cb ^ 1);
        __syncthreads();
    }

    // reduce 8 group-partials per (b, o)
    red[t] = acc0 + acc1;
    __syncthreads();
    if (t < 32) {
        float sum = red[t];
        #pragma unroll
        for (int gg = 1; gg < 8; ++gg) sum += red[gg * 32 + t];
        out[t * OUT_F + o] = sum;
    }
}

extern "C" void kernel_launch(void* const* d_in, const int* in_sizes, int n_in,
                              void* d_out, int out_size, void* d_ws, size_t ws_size,
                              hipStream_t stream) {
    const float* x = (const float*)d_in[0];
    const float* w = (const float*)d_in[1];
    float*       out = (float*)d_out;
    piecewise_fused<<<OUT_F, 256, 0, stream>>>(x, w, out);
}